// Round 1
// baseline (44.181 us; speedup 1.0000x reference)
//
#include <hip/hip_runtime.h>

#define ROWS 64
#define HSTRIDE 93   // 93 % 32 = 29 (odd) -> conflict-free LDS row stride
#define LMAX 92      // only h[0..91] can reach the output
#define TCOLS 400

__global__ __launch_bounds__(256) void pde_fused_kernel(
    const float* __restrict__ x,        // (B, 400)
    const float* __restrict__ wh_rec,   // (1,2)
    const float* __restrict__ wx_rec,   // (2,2)
    const float* __restrict__ wx_eval,  // (2,2)
    const float* __restrict__ wh_eval,  // (2,)
    const float* __restrict__ b_eval,   // (2,)
    const float* __restrict__ conv_w,   // (3,3,4)
    const float* __restrict__ conv_b,   // (3,)
    const float* __restrict__ fc_w,     // (3,12)
    const float* __restrict__ fc_b,     // (3,)
    float* __restrict__ out,            // (B, 3)
    long long Btot)
{
    __shared__ float hlds[ROWS * HSTRIDE];
    const int tid = threadIdx.x;
    const long long r0 = (long long)blockIdx.x * ROWS;

    // ---- Phase 1: coalesced x load, 4->1 mean into LDS ----
    for (int i = tid; i < ROWS * LMAX; i += 256) {
        const int r = i / LMAX;
        const int l = i - r * LMAX;
        const long long row = r0 + r;
        if (row < Btot) {
            const float4 xv = *reinterpret_cast<const float4*>(x + row * TCOLS + l * 4);
            hlds[r * HSTRIDE + l] = (xv.x + xv.y + xv.z + xv.w) * 0.25f;
        }
    }
    __syncthreads();

    if (tid >= ROWS) return;
    const long long row = r0 + tid;
    if (row >= Btot) return;

    // ---- small weights (uniform addresses -> scalar loads) ----
    const float whr0 = wh_rec[0], whr1 = wh_rec[1];
    const float wxr00 = wx_rec[0], wxr01 = wx_rec[1];
    const float wxr10 = wx_rec[2], wxr11 = wx_rec[3];
    const float we00 = wx_eval[0], we01 = wx_eval[1];
    const float we10 = wx_eval[2], we11 = wx_eval[3];
    const float whe0 = wh_eval[0], whe1 = wh_eval[1];
    const float be0 = b_eval[0], be1 = b_eval[1];

    float cw[36], cb[3], fw[36], fb[3];
#pragma unroll
    for (int i = 0; i < 36; i++) cw[i] = conv_w[i];
#pragma unroll
    for (int i = 0; i < 3; i++) cb[i] = conv_b[i];
#pragma unroll
    for (int i = 0; i < 36; i++) fw[i] = fc_w[i];
#pragma unroll
    for (int i = 0; i < 3; i++) fb[i] = fc_b[i];

    const float* __restrict__ hr = &hlds[tid * HSTRIDE];

    // ---- Phase 2: scan + eval + 4-pool fused, all-constant indexing ----
    float f0[23], f1[23], f2[23];
    float c0 = 0.f, c1 = 0.f;          // scan carry
    float cur0 = 0.f, cur1 = 0.f;      // x_rec[l]   = out_{l-2}
    float prv0 = 0.f, prv1 = 0.f;      // x_rec[l-1] = out_{l-3}
    float hprev = 0.f, h0save = 0.f;
    float p0 = 0.f, p1 = 0.f, p2 = 0.f;

#pragma unroll
    for (int l = 0; l < LMAX; l++) {
        const float hl = hr[l];
        if (l == 0) h0save = hl;
        float ev0 = 0.f, ev1 = 0.f;
        if (l >= 2) {
            // scan step producing out_{l-2}; input hseq[l-2] = (l==2 ? h[0] : h[l-1])
            const float hin = (l == 2) ? h0save : hprev;
            const float n0 = fmaf(c0, wxr00, fmaf(c1, wxr10, hin * whr0));
            const float n1 = fmaf(c0, wxr01, fmaf(c1, wxr11, hin * whr1));
            prv0 = cur0; prv1 = cur1;
            cur0 = n0;   cur1 = n1;
            c0 = n0;     c1 = n1;

            const float hterm = (l == 2) ? h0save : hprev;  // h_term[l]
            const float xc0 = (l >= 3) ? cur0 : 0.f;
            const float xc1 = (l >= 3) ? cur1 : 0.f;
            const float xp0 = (l >= 4) ? prv0 : 0.f;
            const float xp1 = (l >= 4) ? prv1 : 0.f;
            ev0 = fmaf(xp0, we00, fmaf(xc0, we01, fmaf(hterm, whe0, be0)));
            ev1 = fmaf(xp1, we10, fmaf(xc1, we11, fmaf(hterm, whe1, be1)));
        }
        p0 += hl; p1 += ev0; p2 += ev1;
        if ((l & 3) == 3) {
            const int m = l >> 2;
            f0[m] = p0 * 0.25f; f1[m] = p1 * 0.25f; f2[m] = p2 * 0.25f;
            p0 = 0.f; p1 = 0.f; p2 = 0.f;
        }
        hprev = hl;
    }

    // ---- conv (only p<20 feeds the 5-maxpool) + tanh ----
    float v[12];
#pragma unroll
    for (int o = 0; o < 3; o++) {
#pragma unroll
        for (int g = 0; g < 4; g++) {
            float zmax = -1e30f;
#pragma unroll
            for (int q = 0; q < 5; q++) {
                const int p = g * 5 + q;
                float y = cb[o];
#pragma unroll
                for (int k = 0; k < 4; k++) {
                    y = fmaf(f0[p + k], cw[o * 12 + 0 + k], y);
                    y = fmaf(f1[p + k], cw[o * 12 + 4 + k], y);
                    y = fmaf(f2[p + k], cw[o * 12 + 8 + k], y);
                }
                zmax = fmaxf(zmax, y);
            }
            v[o * 4 + g] = tanhf(zmax);
        }
    }

    // ---- FC + softmax ----
    float lg0 = fb[0], lg1 = fb[1], lg2 = fb[2];
#pragma unroll
    for (int d = 0; d < 12; d++) {
        lg0 = fmaf(v[d], fw[d], lg0);
        lg1 = fmaf(v[d], fw[12 + d], lg1);
        lg2 = fmaf(v[d], fw[24 + d], lg2);
    }
    const float mx = fmaxf(lg0, fmaxf(lg1, lg2));
    const float e0 = __expf(lg0 - mx);
    const float e1 = __expf(lg1 - mx);
    const float e2 = __expf(lg2 - mx);
    const float inv = 1.f / (e0 + e1 + e2);
    out[row * 3 + 0] = e0 * inv;
    out[row * 3 + 1] = e1 * inv;
    out[row * 3 + 2] = e2 * inv;
}

extern "C" void kernel_launch(void* const* d_in, const int* in_sizes, int n_in,
                              void* d_out, int out_size, void* d_ws, size_t ws_size,
                              hipStream_t stream) {
    const float* x       = (const float*)d_in[0];
    const float* wh_rec  = (const float*)d_in[1];
    const float* wx_rec  = (const float*)d_in[2];
    const float* wx_eval = (const float*)d_in[3];
    const float* wh_eval = (const float*)d_in[4];
    const float* b_eval  = (const float*)d_in[5];
    const float* conv_w  = (const float*)d_in[6];
    const float* conv_b  = (const float*)d_in[7];
    const float* fc_w    = (const float*)d_in[8];
    const float* fc_b    = (const float*)d_in[9];
    float* out = (float*)d_out;

    const long long B = (long long)in_sizes[0] / TCOLS;
    const int nblocks = (int)((B + ROWS - 1) / ROWS);

    pde_fused_kernel<<<nblocks, 256, 0, stream>>>(
        x, wh_rec, wx_rec, wx_eval, wh_eval, b_eval,
        conv_w, conv_b, fc_w, fc_b, out, B);
}